// Round 6
// baseline (831.003 us; speedup 1.0000x reference)
//
#include <hip/hip_runtime.h>
#include <hip/hip_fp16.h>

typedef _Float16 f16x8 __attribute__((ext_vector_type(8)));
typedef _Float16 f16x4 __attribute__((ext_vector_type(4)));
typedef _Float16 f16x2 __attribute__((ext_vector_type(2)));
typedef float f32x4 __attribute__((ext_vector_type(4)));
typedef short s16x8 __attribute__((ext_vector_type(8)));

typedef __attribute__((address_space(1))) void gvoid;
typedef __attribute__((address_space(3))) void lvoid;

#define GLD_LDS16(g, l) __builtin_amdgcn_global_load_lds((gvoid*)(g), (lvoid*)(l), 16, 0, 0)
#define BAR() __builtin_amdgcn_s_barrier()

// ---- fp32 -> fp16 downcast, 8 elems/thread, 16B stores ----
__global__ __launch_bounds__(256) void cvt_f32_f16(
    const float* __restrict__ src, _Float16* __restrict__ dst, int n8)
{
    const int i = blockIdx.x * 256 + threadIdx.x;
    if (i >= n8) return;
    const float4* s = (const float4*)src;
    const float4 a = s[2 * i], b = s[2 * i + 1];
    f16x8 o;
    o[0] = (_Float16)a.x; o[1] = (_Float16)a.y; o[2] = (_Float16)a.z; o[3] = (_Float16)a.w;
    o[4] = (_Float16)b.x; o[5] = (_Float16)b.y; o[6] = (_Float16)b.z; o[7] = (_Float16)b.w;
    *(f16x8*)(dst + (size_t)i * 8) = o;
}

// ============================================================================
// C[M,N] = A[M,K] @ B[N,K]^T + bias[N]; f16 in, fp32 acc, OutT out.
// 256x256 tile, BK=64, 512 threads (8 waves, 2M x 4N), 16x16x32 f16 MFMA.
// r6: DEEP prefetch — tile t stages tile t+2 (same dbuf d=t&1) at ph3/ph4,
// so tile t+1's loads (issued during t-1) have 5-7 phases (~1500cy) of cover.
// Tile-end wait is vmcnt(8): the 8 outstanding loads are t+2's; everything
// older (all of t+1) has retired. The wait is ~free (was: vmcnt(2) waiting
// on loads issued 1-3 phases back => ~600cy stall/tile, MfmaUtil 48%).
//
// Write-after-read ledger (buf d quarters, tile t reads d):
//   B0,B1(d) last read t.ph2 (RD_B d,0 @ph1; RD_B d,1 @ph2; reads complete
//     before ph2 MFMA via lgkmcnt, all waves past ph2.BAR2 before ph3 issues)
//   A0,A1(d) last read t.ph3 (RD_A d,1) -> staged at t.ph4 after ph3.BAR2.
//   STAGE(2,3 of t+2)->d at t.ph3;  STAGE(0,1 of t+2)->d at t.ph4.  SAFE.
// In-flight at t end: 8 (t+2's). vmcnt(8) => t+1 fully landed. BAR. proceed.
// ============================================================================
template <typename OutT>
__global__ __launch_bounds__(512, 1) void gemm_bt_bias(
    const _Float16* __restrict__ A, int lda,
    const _Float16* __restrict__ B,        // ldb == K
    const float* __restrict__ bias,
    OutT* __restrict__ C, int ldc,
    int K, int nbx)
{
    __shared__ alignas(16) _Float16 smem[65536];   // 128 KiB

    const int tid = threadIdx.x;
    const int lane = tid & 63, wv = tid >> 6;
    const int nwg = gridDim.x;
    int bid = blockIdx.x;
    if ((nwg & 7) == 0) bid = (bid & 7) * (nwg >> 3) + (bid >> 3);
    const int m0 = (bid / nbx) * 256, n0 = (bid % nbx) * 256;
    const int wm = wv >> 2, wn = wv & 3;            // wave -> 128x64 sub-tile
    const int l15 = lane & 15, q4 = lane >> 4, l7 = lane & 7;
    const int nk = K >> 6;

    const int rl = tid >> 3;
    const int cl = (tid & 7) ^ (rl & 7);
    const _Float16* gp00 = A + (size_t)(m0 + rl) * lda + cl * 8;
    const _Float16* gp01 = A + (size_t)(m0 + 64 + rl) * lda + cl * 8;
    const _Float16* gp10 = A + (size_t)(m0 + 128 + rl) * lda + cl * 8;
    const _Float16* gp11 = A + (size_t)(m0 + 192 + rl) * lda + cl * 8;
    const _Float16* gp20 = B + (size_t)(n0 + rl) * (size_t)K + cl * 8;
    const _Float16* gp21 = B + (size_t)(n0 + 64 + rl) * (size_t)K + cl * 8;
    const _Float16* gp30 = B + (size_t)(n0 + 128 + rl) * (size_t)K + cl * 8;
    const _Float16* gp31 = B + (size_t)(n0 + 192 + rl) * (size_t)K + cl * 8;

    f32x4 acc[8][4];
#pragma unroll
    for (int i = 0; i < 8; ++i)
#pragma unroll
        for (int j = 0; j < 4; ++j)
            acc[i][j] = (f32x4){0.f, 0.f, 0.f, 0.f};

    f16x8 fa[4][2], fb0[2][2], fb1[2][2];

#define STAGE(J, tile_) do {                                                  \
    const int dd_ = (tile_) & 1;                                              \
    _Float16* lb_ = &smem[dd_ * 32768 + ((J) >> 1) * 16384 +                  \
                          ((J) & 1) * 8192 + wv * 512];                       \
    const size_t ko_ = (size_t)(tile_) * 64;                                  \
    GLD_LDS16(gp##J##0 + ko_, lb_);                                           \
    GLD_LDS16(gp##J##1 + ko_, lb_ + 4096);                                    \
} while (0)

#define RD_A(d_, mq_) do {                                                    \
    const _Float16* ba_ = &smem[(d_) * 32768];                                \
    _Pragma("unroll")                                                         \
    for (int fi = 0; fi < 4; ++fi) {                                          \
        const int r_ = wm * 128 + (mq_) * 64 + fi * 16 + l15;                 \
        fa[fi][0] = *(const f16x8*)(ba_ + r_ * 64 + ((q4 ^ l7) * 8));         \
        fa[fi][1] = *(const f16x8*)(ba_ + r_ * 64 + (((4 + q4) ^ l7) * 8));   \
    }                                                                         \
} while (0)

#define RD_B(d_, nq_, fbv) do {                                               \
    const _Float16* bb_ = &smem[(d_) * 32768 + 16384];                        \
    _Pragma("unroll")                                                         \
    for (int fj = 0; fj < 2; ++fj) {                                          \
        const int r_ = wn * 64 + (nq_) * 32 + fj * 16 + l15;                  \
        fbv[fj][0] = *(const f16x8*)(bb_ + r_ * 64 + ((q4 ^ l7) * 8));        \
        fbv[fj][1] = *(const f16x8*)(bb_ + r_ * 64 + (((4 + q4) ^ l7) * 8));  \
    }                                                                         \
} while (0)

#define MM(mq_, nq_, fbv) do {                                                \
    __builtin_amdgcn_s_setprio(1);                                            \
    _Pragma("unroll")                                                         \
    for (int ks = 0; ks < 2; ++ks)                                            \
    _Pragma("unroll")                                                         \
    for (int fi = 0; fi < 4; ++fi)                                            \
    _Pragma("unroll")                                                         \
    for (int fj = 0; fj < 2; ++fj)                                            \
        acc[(mq_) * 4 + fi][(nq_) * 2 + fj] =                                 \
            __builtin_amdgcn_mfma_f32_16x16x32_f16(                           \
                fa[fi][ks], fbv[fj][ks],                                      \
                acc[(mq_) * 4 + fi][(nq_) * 2 + fj], 0, 0, 0);                \
    __builtin_amdgcn_s_setprio(0);                                            \
} while (0)

// SB = stage B-quarters of t+2 (at ph3), SA = stage A-quarters (at ph4)
#define GTILE(d_, SB, SA, VMN) do {                                           \
    RD_A(d_, 0); RD_B(d_, 0, fb0);                                           \
    BAR(); MM(0, 0, fb0); BAR();                                              \
    RD_B(d_, 1, fb1);                                                         \
    BAR(); MM(0, 1, fb1); BAR();                                              \
    RD_A(d_, 1);                                                              \
    SB;                                                                       \
    BAR(); MM(1, 1, fb1); BAR();                                              \
    SA;                                                                       \
    BAR(); MM(1, 0, fb0);                                                     \
    asm volatile("s_waitcnt vmcnt(" #VMN ")" ::: "memory");                   \
    BAR();                                                                    \
} while (0)

#define SB2(tile_) do { STAGE(2, tile_); STAGE(3, tile_); } while (0)
#define SA2(tile_) do { STAGE(0, tile_); STAGE(1, tile_); } while (0)

    // prologue: stage t0 and t1 fully; wait for t0 (t1's 8 remain in flight)
    STAGE(0, 0); STAGE(1, 0); STAGE(2, 0); STAGE(3, 0);
    if (nk > 1) {
        STAGE(0, 1); STAGE(1, 1); STAGE(2, 1); STAGE(3, 1);
        asm volatile("s_waitcnt vmcnt(8)" ::: "memory");
    } else {
        asm volatile("s_waitcnt vmcnt(0)" ::: "memory");
    }
    BAR();

    for (int kt = 0; kt < nk - 2; ++kt) {
        const int d = kt & 1;
        GTILE(d, SB2(kt + 2), SA2(kt + 2), 8);
    }
    if (nk >= 2) {
        // tile nk-2: nothing to stage; drain (tile nk-1's loads are 2 tiles
        // old => wait ~free)
        GTILE((nk - 2) & 1, (void)0, (void)0, 0);
    }
    {   // last tile: no staging, no barriers needed
        const int d = (nk - 1) & 1;
        RD_A(d, 0); RD_B(d, 0, fb0);
        MM(0, 0, fb0);
        RD_B(d, 1, fb1);
        MM(0, 1, fb1);
        RD_A(d, 1);
        MM(1, 1, fb1);
        MM(1, 0, fb0);
    }

#undef SB2
#undef SA2
#undef GTILE
#undef MM
#undef RD_B
#undef RD_A
#undef STAGE

    // epilogue: 16x16 C/D layout col=lane&15, row=(lane>>4)*4+reg
#pragma unroll
    for (int nj = 0; nj < 4; ++nj) {
        const int col = n0 + wn * 64 + nj * 16 + l15;
        const float bs = bias[col];
#pragma unroll
        for (int mi = 0; mi < 8; ++mi) {
            const int row = m0 + wm * 128 + mi * 16 + q4 * 4;
#pragma unroll
            for (int i = 0; i < 4; ++i)
                C[(size_t)(row + i) * ldc + col] = (OutT)(acc[mi][nj][i] + bs);
        }
    }
}

// ============================================================================
// Fused attention per (b,h) — r2-EXACT version (best measured: 799.4 total).
// Swapped-operand S^T = K Q^T, in-register query-axis softmax (4-reg reduce
// + 4x shfl_xor), causal mask in-register, P packed f16x4 ds_write_b64,
// V transposed chunk-rotated for b128 PV reads. Scattered scalar O-stores
// (measured equal to LDS-bounce coalesced stores in r4). K staged in LDS
// (r5's K-from-global regressed ~+15us: 16B/lane at 12KB stride).
// LDS 53248B -> 3 blocks/CU. grid = 4096 blocks x 256 threads. FROZEN.
// ============================================================================
__global__ __launch_bounds__(256, 3) void attn_fused(_Float16* __restrict__ qkv)
{
    constexpr float SCALE = 0.022097086912079608f; // 1/sqrt(2048)
    __shared__ alignas(16) char smem[53248];
    _Float16* sQ  = (_Float16*)smem;             // [64][136]
    _Float16* sK  = (_Float16*)(smem + 17408);   // [64][136]
    _Float16* sVT = (_Float16*)(smem + 34816);   // [128][72] chunk-rotated V^T
    _Float16* sP  = (_Float16*)smem;             // [64][72]  P[q][k], aliases sQ

    const int t = threadIdx.x;
    const int bh = blockIdx.x;
    const int b = bh >> 4, h = bh & 15;
    const int ld = 6144;
    const _Float16* Qg = qkv + (size_t)b * 64 * ld + h * 128;
    const _Float16* Kg = Qg + 2048;
    const _Float16* Vg = Qg + 4096;
    _Float16* Og = qkv + (size_t)b * 64 * ld + h * 128;

    const int lane = t & 63, w = t >> 6;
    const int l15 = lane & 15, q4 = lane >> 4;

    // ---- load: Q,K row-major [64][136]; V transposed chunk-rotated ----
#pragma unroll
    for (int j = 0; j < 4; ++j) {
        const int i = t + j * 256;
        const int r = i >> 4, c = (i & 15) * 8;       // r = k-row, c = d base
        *(s16x8*)(sQ + r * 136 + c) = *(const s16x8*)(Qg + (size_t)r * ld + c);
        *(s16x8*)(sK + r * 136 + c) = *(const s16x8*)(Kg + (size_t)r * ld + c);
        const f16x8 vv = *(const f16x8*)(Vg + (size_t)r * ld + c);
        const int cp = ((r >> 3) + (c >> 3)) & 7;     // rotated chunk position
#pragma unroll
        for (int p = 0; p < 8; ++p)
            sVT[(c + p) * 72 + cp * 8 + (r & 7)] = vv[p];
    }
    __syncthreads();

    // ---- S^T = K Q^T: wave w owns keys [w*16, w*16+16) x all 64 queries ----
    f32x4 sc[4];
#pragma unroll
    for (int nt = 0; nt < 4; ++nt) sc[nt] = (f32x4){0.f, 0.f, 0.f, 0.f};
#pragma unroll
    for (int kk = 0; kk < 4; ++kk) {
        const f16x8 ak = *(const f16x8*)(sK + (w * 16 + l15) * 136 + kk * 32 + q4 * 8);
#pragma unroll
        for (int nt = 0; nt < 4; ++nt) {
            const f16x8 bq = *(const f16x8*)(sQ + (nt * 16 + l15) * 136 + kk * 32 + q4 * 8);
            sc[nt] = __builtin_amdgcn_mfma_f32_16x16x32_f16(ak, bq, sc[nt], 0, 0, 0);
        }
    }

    // ---- causal mask + scale, in-register ----
    const int key0 = w * 16 + q4 * 4;
#pragma unroll
    for (int nt = 0; nt < 4; ++nt) {
        const int q = nt * 16 + l15;
#pragma unroll
        for (int i = 0; i < 4; ++i)
            sc[nt][i] = (q >= key0 + i) ? sc[nt][i] * SCALE : -3.0e38f;
    }

    // ---- softmax over q per key: 4-reg reduce + shfl_xor over l15 group ----
    float mx[4], sm[4];
#pragma unroll
    for (int i = 0; i < 4; ++i)
        mx[i] = fmaxf(fmaxf(sc[0][i], sc[1][i]), fmaxf(sc[2][i], sc[3][i]));
#pragma unroll
    for (int m = 1; m <= 8; m <<= 1)
#pragma unroll
        for (int i = 0; i < 4; ++i)
            mx[i] = fmaxf(mx[i], __shfl_xor(mx[i], m, 64));
#pragma unroll
    for (int i = 0; i < 4; ++i) sm[i] = 0.f;
#pragma unroll
    for (int nt = 0; nt < 4; ++nt)
#pragma unroll
        for (int i = 0; i < 4; ++i) {
            const float e = __expf(sc[nt][i] - mx[i]);  // masked -> 0
            sc[nt][i] = e;
            sm[i] += e;
        }
#pragma unroll
    for (int m = 1; m <= 8; m <<= 1)
#pragma unroll
        for (int i = 0; i < 4; ++i)
            sm[i] += __shfl_xor(sm[i], m, 64);
    float inv[4];
#pragma unroll
    for (int i = 0; i < 4; ++i) inv[i] = 1.0f / sm[i];

    __syncthreads();   // all waves done reading sQ/sK before sP overwrite

    // ---- P[q][k] f16, packed 4 consecutive k per lane -> ds_write_b64 ----
#pragma unroll
    for (int nt = 0; nt < 4; ++nt) {
        f16x4 pk;
#pragma unroll
        for (int i = 0; i < 4; ++i)
            pk[i] = (_Float16)(sc[nt][i] * inv[i]);
        *(f16x4*)(sP + (nt * 16 + l15) * 72 + w * 16 + q4 * 4) = pk;
    }
    __syncthreads();

    // ---- O = P V: wave w does q-rows [w*16,+16) x 128 dims, all b128 ----
    f32x4 oa[8];
#pragma unroll
    for (int nt = 0; nt < 8; ++nt) oa[nt] = (f32x4){0.f, 0.f, 0.f, 0.f};
#pragma unroll
    for (int ks = 0; ks < 2; ++ks) {
        const int cc = ks * 4 + q4;                   // k-chunk 0..7
        const f16x8 ap = *(const f16x8*)(sP + (w * 16 + l15) * 72 + cc * 8);
#pragma unroll
        for (int nt = 0; nt < 8; ++nt) {
            const int dd = nt * 16 + l15;
            const f16x8 bv = *(const f16x8*)(sVT + dd * 72 + ((cc + (dd >> 3)) & 7) * 8);
            oa[nt] = __builtin_amdgcn_mfma_f32_16x16x32_f16(ap, bv, oa[nt], 0, 0, 0);
        }
    }

    // ---- store O over Q region ----
#pragma unroll
    for (int nt = 0; nt < 8; ++nt)
#pragma unroll
        for (int i = 0; i < 4; ++i)
            Og[(size_t)(w * 16 + q4 * 4 + i) * ld + nt * 16 + l15] =
                (_Float16)(oa[nt][i]);
}

extern "C" void kernel_launch(void* const* d_in, const int* in_sizes, int n_in,
                              void* d_out, int out_size, void* d_ws, size_t ws_size,
                              hipStream_t stream) {
    const float* x     = (const float*)d_in[0]; // [16384,2048] fp32
    const float* W_qkv = (const float*)d_in[1]; // [6144,2048]  fp32
    const float* b_qkv = (const float*)d_in[2]; // [6144]       fp32
    const float* W_out = (const float*)d_in[3]; // [2048,2048]  fp32
    const float* b_out = (const float*)d_in[4]; // [2048]       fp32
    float* out = (float*)d_out;                 // [16384,2048] fp32

    char* ws = (char*)d_ws;
    _Float16* qkv = (_Float16*)ws;                    // [16384,6144] f16
    _Float16* xh  = (_Float16*)(ws + 201326592);      // [16384,2048] f16
    _Float16* wqh = (_Float16*)(ws + 268435456);      // [6144,2048]  f16
    _Float16* woh = wqh;  // W_out reuses slot after GEMM1 consumed W_qkv

    // 0) downcast inputs
    cvt_f32_f16<<<dim3(33554432 / 2048), 256, 0, stream>>>(x, xh, 33554432 / 8);
    cvt_f32_f16<<<dim3(12582912 / 2048), 256, 0, stream>>>(W_qkv, wqh, 12582912 / 8);
    // 1) qkv = x @ W_qkv^T + b_qkv   (f16 out into ws); 64x24 = 1536 blocks
    gemm_bt_bias<_Float16><<<dim3(1536), 512, 0, stream>>>(
        xh, 2048, wqh, b_qkv, qkv, 6144, 2048, 24);
    // 1b) downcast W_out into the dead W_qkv slot
    cvt_f32_f16<<<dim3(4194304 / 2048), 256, 0, stream>>>(W_out, woh, 4194304 / 8);
    // 2) fused attention per (b,h); output overwrites q-region of qkv
    attn_fused<<<dim3(4096), 256, 0, stream>>>(qkv);
    // 3) out = attn_out @ W_out^T + b_out  (fp32 out); 64x8 = 512 blocks
    gemm_bt_bias<float><<<dim3(512), 512, 0, stream>>>(
        qkv, 6144, woh, b_out, out, 2048, 2048, 8);
}